// Round 15
// baseline (665.558 us; speedup 1.0000x reference)
//
#include <hip/hip_runtime.h>
#include <cstddef>

#define HID 64
#define TT 64
#define NFEAT 8
#define TOUTC 12
#define SPB 8           // 8 seqs/block; MFMA cols duplicated, activation folded across lane halves
#define NBLK 1024
#define NTHR 256

typedef float f4 __attribute__((ext_vector_type(4)));
typedef _Float16 h8 __attribute__((ext_vector_type(8)));
typedef unsigned int u32;
typedef unsigned long long u64;

#define MFMA16 __builtin_amdgcn_mfma_f32_16x16x32_f16
#define LOG2E 1.44269504088896340736f

// Scaled-domain activations (weights/bias pre-scaled by log2e; gate g by 2*log2e):
__device__ __forceinline__ float sigm_s(float xs) {
    float e = __builtin_amdgcn_exp2f(-xs);
    return __builtin_amdgcn_rcpf(1.0f + e);
}
__device__ __forceinline__ float tanh_s(float xs2) {
    float e = __builtin_amdgcn_exp2f(xs2);
    return 1.0f - 2.0f * __builtin_amdgcn_rcpf(e + 1.0f);
}

// Barrier: drain LDS, raw barrier, allow everything EXCEPT DS to cross.
#define STEP_BAR() do {                                         \
    asm volatile("s_waitcnt lgkmcnt(0)" ::: "memory");          \
    __builtin_amdgcn_s_barrier();                               \
    __builtin_amdgcn_sched_barrier(0x7F);                       \
} while (0)

// LDS: zh [2][16][64] fp16 (4096 B, swizzle byte ^= (row&7)<<4), hs f32[16][68].
// zh seq-rows 8..15 duplicate rows 0..7 (written every step) so MFMA cols 8-15
// are valid/deterministic. ws: fp16 [seq][t][HID]; dbuf across layers.
//
// MFMA 16x16x32 f16, single chain (W fp16-RN scaled by log2e / 2log2e):
//   acc = bias (C-init) + Wx*x(t+1)  [shadow, end of step t]
//   acc += Wh*h(t)                   [post-barrier serial work]
// A frag: row=l&15, k=8*(l>>4)+j. B frag: col=l&15. C/D: col=l&15, row=4*(l>>4)+r.
// Fold: lanes cs<8 keep rows {0,1}; lanes cs>=8 take rows {2,3} of seq cs-8 via
// shfl_xor(8) -> 2 cells/lane (R10-verified exact). Static indexing only (rule #20).
template<int KSX, bool FIRST, bool LAST>
__device__ __forceinline__ void run_layer(
    const float* __restrict__ Wih, const float* __restrict__ Whh,
    const float* __restrict__ bi,  const float* __restrict__ bh_,
    const float* __restrict__ Xj,
    const unsigned short* __restrict__ rbuf, unsigned short* __restrict__ wbuf,
    char* zh, float* hs, int tid, int seq0)
{
    constexpr int NKS = KSX + 2;
    const int lane = tid & 63;
    const int wv   = tid >> 6;
    const int cs   = lane & 15;
    const int rq   = lane >> 4;
    const int hb   = 16 * wv + 4 * rq;
    const int swz  = (cs & 7) << 4;
    const int seqL = cs & 7;
    const int h0   = (cs >> 3) & 1;
    const int seq  = seq0 + seqL;

    f4 z4 = {0.f, 0.f, 0.f, 0.f};

    // ---- weight A-fragments: single fp16 (RN), pre-scaled (2log2e for gate g) ----
    h8 Ah[4][NKS];
#pragma unroll
    for (int a = 0; a < 4; ++a) {
        const float sA = (a == 2) ? (2.0f * LOG2E) : LOG2E;
        const int row = 64 * a + 16 * wv + cs;
#pragma unroll
        for (int ks = 0; ks < NKS; ++ks) {
            float v[8];
            if (ks < KSX) {
                if (FIRST) {
                    const float* p = Wih + (size_t)row * NFEAT;
#pragma unroll
                    for (int j = 0; j < 8; ++j) v[j] = (rq == 0) ? p[j] : 0.0f;
                } else {
                    const float* p = Wih + (size_t)row * HID + 32 * ks + 8 * rq;
#pragma unroll
                    for (int j = 0; j < 8; ++j) v[j] = p[j];
                }
            } else {
                const float* p = Whh + (size_t)row * HID + 32 * (ks - KSX) + 8 * rq;
#pragma unroll
                for (int j = 0; j < 8; ++j) v[j] = p[j];
            }
#pragma unroll
            for (int j = 0; j < 8; ++j) Ah[a][ks][j] = (_Float16)(v[j] * sA);
        }
    }

    // ---- bias (C/D layout), scaled — MFMA C-init ----
    f4 bias[4];
#pragma unroll
    for (int a = 0; a < 4; ++a) {
        const float sA = (a == 2) ? (2.0f * LOG2E) : LOG2E;
        f4 b = *(const f4*)(bi + 64 * a + hb) + *(const f4*)(bh_ + 64 * a + hb);
#pragma unroll
        for (int r = 0; r < 4; ++r) b[r] *= sA;
        bias[a] = b;
    }

    // ---- zero both zh planes (4096 B = 1024 u32) ----
#pragma unroll
    for (int i = 0; i < 4; ++i)
        ((u32*)zh)[tid * 4 + i] = 0u;

    float c0a = 0.f, c0b = 0.f;   // 2 cells per lane (fold)
    f4 acc[4];

    // ---- single prefetch set (consume -> refill; 1-step latency window) ----
    h8 xS[KSX];
    f4 fS[2];

    auto PREF = [&](int t) {
        if constexpr (FIRST) {
            if (rq == 0) {
                const float* pX = Xj + ((size_t)seq * TT + t) * NFEAT;
                fS[0] = *(const f4*)pX;
                fS[1] = *(const f4*)(pX + 4);
            } else {
                fS[0] = z4; fS[1] = z4;
            }
        } else {
            const unsigned short* pR = rbuf + ((size_t)seq * TT + t) * HID + 8 * rq;
#pragma unroll
            for (int ks = 0; ks < KSX; ++ks)
                xS[ks] = *(const h8*)(pR + 32 * ks);
        }
    };

    // x-part MFMAs: acc = bias + Wx*x (consumes xS/fS)
    auto XMF = [&]() {
        h8 bx[KSX];
        if constexpr (FIRST) {
#pragma unroll
            for (int j = 0; j < 4; ++j) {
                bx[0][j]     = (_Float16)fS[0][j];
                bx[0][4 + j] = (_Float16)fS[1][j];
            }
        } else {
#pragma unroll
            for (int ks = 0; ks < KSX; ++ks) bx[ks] = xS[ks];
        }
#pragma unroll
        for (int a = 0; a < 4; ++a) {
            acc[a] = MFMA16(Ah[a][0], bx[0], bias[a], 0, 0, 0);
            if constexpr (KSX == 2)
                acc[a] = MFMA16(Ah[a][1], bx[1], acc[a], 0, 0, 0);
        }
    };

    auto STEPB = [&](int t, int p) {
        // ---- h B-fragments from LDS (swizzled) ----
        h8 bhh[2];
#pragma unroll
        for (int kk = 0; kk < 2; ++kk) {
            const int ho = p * 2048 + ((cs * 128 + 64 * kk + 16 * rq) ^ swz);
            bhh[kk] = *(const h8*)(zh + ho);
        }

        // ---- serial MFMA work: h-part only ----
        __builtin_amdgcn_s_setprio(1);
#pragma unroll
        for (int a = 0; a < 4; ++a) {
            acc[a] = MFMA16(Ah[a][KSX + 0], bhh[0], acc[a], 0, 0, 0);
            acc[a] = MFMA16(Ah[a][KSX + 1], bhh[1], acc[a], 0, 0, 0);
        }
        __builtin_amdgcn_s_setprio(0);

        // ---- gate fold: lanes cs>=8 take rows {2,3} of partner seq ----
        float ga0[4], ga1[4];
#pragma unroll
        for (int a = 0; a < 4; ++a) {
            float x2 = __shfl_xor(acc[a][2], 8);
            float x3 = __shfl_xor(acc[a][3], 8);
            ga0[a] = h0 ? x2 : acc[a][0];
            ga1[a] = h0 ? x3 : acc[a][1];
        }

        // ---- activations (scaled domain): 2 cells per lane ----
        float hv0, hv1;
        {
            float ig = sigm_s(ga0[0]), fg = sigm_s(ga0[1]);
            float gg = tanh_s(ga0[2]), og = sigm_s(ga0[3]);
            float cc = fg * c0a + ig * gg;
            c0a = cc;
            hv0 = og * tanh_s(cc * (2.0f * LOG2E));
        }
        {
            float ig = sigm_s(ga1[0]), fg = sigm_s(ga1[1]);
            float gg = tanh_s(ga1[2]), og = sigm_s(ga1[3]);
            float cc = fg * c0b + ig * gg;
            c0b = cc;
            hv1 = og * tanh_s(cc * (2.0f * LOG2E));
        }

        // ---- pack 2 fp16 in one op; write zh ping (both dup rows) + ws ----
        u32 ph = __builtin_bit_cast(u32, __builtin_amdgcn_cvt_pkrtz(hv0, hv1));
        const int elem = hb + 2 * h0;
        {
            const int base = (1 ^ p) * 2048;
            const int wo0 = base + ((seqL * 128 + 2 * elem) ^ swz);
            const int wo1 = base + (((seqL + 8) * 128 + 2 * elem) ^ swz);
            *(u32*)(zh + wo0) = ph;
            *(u32*)(zh + wo1) = ph;
        }
        if constexpr (!LAST) {
            *(u32*)(wbuf + ((size_t)seq * TT + t) * HID + elem) = ph;
        } else {
            if (t == TT - 1) {
                float o0 = __shfl_xor(hv0, 8);
                float o1 = __shfl_xor(hv1, 8);
                if (!h0) {
                    f4 hvec = {hv0, hv1, o0, o1};
                    *(f4*)(hs + cs * 68 + hb) = hvec;
                }
            }
        }

        // ---- shadow: x-MFMAs of t+1 (consume xS), refill xS with x(t+2) ----
        if (t + 1 < TT) XMF();
        if (t + 2 < TT) PREF(t + 2);

        STEP_BAR();
    };

    PREF(0);
    __syncthreads();   // drains vmcnt (PREF + prev-layer ws stores) + zh zero visible

    XMF();             // x-part of step 0 (consumes x(0))
    PREF(1);

#pragma unroll 1
    for (int tb = 0; tb < TT; tb += 2) {
        STEPB(tb,     0);
        STEPB(tb + 1, 1);
    }
}

__global__ __launch_bounds__(NTHR, 4)
void lstm_mfma16(const float* __restrict__ Xj,
                 const float* __restrict__ Wih0, const float* __restrict__ Whh0,
                 const float* __restrict__ bih0, const float* __restrict__ bhh0,
                 const float* __restrict__ WihR, const float* __restrict__ WhhR,
                 const float* __restrict__ bihR, const float* __restrict__ bhhR,
                 const float* __restrict__ Wout, const float* __restrict__ bout,
                 float* __restrict__ out,
                 unsigned short* __restrict__ ws0, unsigned short* __restrict__ ws1)
{
    __shared__ char smraw[8448];
    char*  zh = smraw;                    // [2][16][64] fp16
    float* hs = (float*)(smraw + 4096);   // [16][68] f32 (rows 0..7 used)

    const int tid  = threadIdx.x;
    const int seq0 = blockIdx.x * SPB;

    run_layer<1, true,  false>(Wih0, Whh0, bih0, bhh0, Xj, ws0, ws0, zh, hs, tid, seq0);
    run_layer<2, false, false>(WihR + (size_t)0 * 256 * HID, WhhR + (size_t)0 * 256 * HID,
                               bihR + 0 * 256, bhhR + 0 * 256, nullptr, ws0, ws1, zh, hs, tid, seq0);
    run_layer<2, false, false>(WihR + (size_t)1 * 256 * HID, WhhR + (size_t)1 * 256 * HID,
                               bihR + 1 * 256, bhhR + 1 * 256, nullptr, ws1, ws0, zh, hs, tid, seq0);
    run_layer<2, false, false>(WihR + (size_t)2 * 256 * HID, WhhR + (size_t)2 * 256 * HID,
                               bihR + 2 * 256, bhhR + 2 * 256, nullptr, ws0, ws1, zh, hs, tid, seq0);
    run_layer<2, false, true >(WihR + (size_t)3 * 256 * HID, WhhR + (size_t)3 * 256 * HID,
                               bihR + 3 * 256, bhhR + 3 * 256, nullptr, ws1, ws0, zh, hs, tid, seq0);

    __syncthreads();
    // ---- output projection: 8 seqs x 12 outs = 96 items ----
    for (int it = tid; it < SPB * TOUTC; it += NTHR) {
        int s = it / TOUTC, o = it % TOUTC;
        float sum = bout[o];
#pragma unroll 8
        for (int j = 0; j < HID; ++j)
            sum = fmaf(Wout[o * HID + j], hs[s * 68 + j], sum);
        out[(size_t)(seq0 + s) * TOUTC + o] = sum;
    }
}

extern "C" void kernel_launch(void* const* d_in, const int* in_sizes, int n_in,
                              void* d_out, int out_size, void* d_ws, size_t ws_size,
                              hipStream_t stream)
{
    const float* Xj   = (const float*)d_in[1];
    const float* Wih0 = (const float*)d_in[3];
    const float* Whh0 = (const float*)d_in[4];
    const float* bih0 = (const float*)d_in[5];
    const float* bhh0 = (const float*)d_in[6];
    const float* WihR = (const float*)d_in[7];
    const float* WhhR = (const float*)d_in[8];
    const float* bihR = (const float*)d_in[9];
    const float* bhhR = (const float*)d_in[10];
    const float* Wout = (const float*)d_in[11];
    const float* bout = (const float*)d_in[12];
    float* out = (float*)d_out;

    unsigned short* ws = (unsigned short*)d_ws;
    const size_t half_elems = (size_t)8192 * TT * HID;   // 33.5M shorts = 67 MB
    const bool dbuf = ws_size >= 2 * half_elems * sizeof(unsigned short);
    unsigned short* ws0 = ws;
    unsigned short* ws1 = dbuf ? (ws + half_elems) : ws;   // in-place fallback (R6-proven)

    lstm_mfma16<<<NBLK, NTHR, 0, stream>>>(Xj, Wih0, Whh0, bih0, bhh0,
                                           WihR, WhhR, bihR, bhhR,
                                           Wout, bout, out, ws0, ws1);
}

// Round 16
// 456.912 us; speedup vs baseline: 1.4566x; 1.4566x over previous
//
#include <hip/hip_runtime.h>
#include <cstddef>

#define HID 64
#define TT 64
#define NFEAT 8
#define TOUTC 12
#define SPB 8           // 8 seqs/block; MFMA cols duplicated, activation folded across lane halves
#define NBLK 1024
#define NTHR 256

typedef float f4 __attribute__((ext_vector_type(4)));
typedef _Float16 h8 __attribute__((ext_vector_type(8)));
typedef unsigned int u32;
typedef unsigned long long u64;

#define MFMA16 __builtin_amdgcn_mfma_f32_16x16x32_f16
#define LOG2E 1.44269504088896340736f

// Scaled-domain activations (weights/bias pre-scaled by log2e; gate g by 2*log2e):
__device__ __forceinline__ float sigm_s(float xs) {
    float e = __builtin_amdgcn_exp2f(-xs);
    return __builtin_amdgcn_rcpf(1.0f + e);
}
__device__ __forceinline__ float tanh_s(float xs2) {
    float e = __builtin_amdgcn_exp2f(xs2);
    return 1.0f - 2.0f * __builtin_amdgcn_rcpf(e + 1.0f);
}

// Barrier: drain LDS, raw barrier, allow everything EXCEPT DS to cross.
#define STEP_BAR() do {                                         \
    asm volatile("s_waitcnt lgkmcnt(0)" ::: "memory");          \
    __builtin_amdgcn_s_barrier();                               \
    __builtin_amdgcn_sched_barrier(0x7F);                       \
} while (0)

// LDS: zh [2][16][64] fp16 (4096 B, swizzle byte ^= (row&7)<<4), hs f32[16][68].
// zh seq-rows 8..15 duplicate rows 0..7 (written every step) so MFMA cols 8-15
// are valid/deterministic. ws: fp16 [seq][t][HID]; dbuf across layers.
//
// MFMA 16x16x32 f16, single chain (W fp16-RN scaled by log2e / 2log2e):
//   acc = bias (C-init) + Wx*x(t+1)  [shadow, end of step t]
//   acc += Wh*h(t)                   [post-barrier serial work]
// A frag: row=l&15, k=8*(l>>4)+j. B frag: col=l&15. C/D: col=l&15, row=4*(l>>4)+r.
// Fold: lanes cs<8 keep rows {0,1}; lanes cs>=8 take rows {2,3} of seq cs-8 via
// shfl_xor(8) -> 2 cells/lane (R10-verified exact). Static indexing only (rule #20).
// NOTE: no aggressive __launch_bounds__ — (256,4) empirically clamps to 64 VGPR
// and spills (R9/R10/R15). (256,2) -> ~104 VGPR; 4 waves/SIMD come from the
// 1024-block grid + floor(512/104)=4 register arithmetic.
template<int KSX, bool FIRST, bool LAST>
__device__ __forceinline__ void run_layer(
    const float* __restrict__ Wih, const float* __restrict__ Whh,
    const float* __restrict__ bi,  const float* __restrict__ bh_,
    const float* __restrict__ Xj,
    const unsigned short* __restrict__ rbuf, unsigned short* __restrict__ wbuf,
    char* zh, float* hs, int tid, int seq0)
{
    constexpr int NKS = KSX + 2;
    const int lane = tid & 63;
    const int wv   = tid >> 6;
    const int cs   = lane & 15;
    const int rq   = lane >> 4;
    const int hb   = 16 * wv + 4 * rq;
    const int swz  = (cs & 7) << 4;
    const int seqL = cs & 7;
    const int h0   = (cs >> 3) & 1;
    const int seq  = seq0 + seqL;

    f4 z4 = {0.f, 0.f, 0.f, 0.f};

    // ---- weight A-fragments: single fp16 (RN), pre-scaled (2log2e for gate g) ----
    h8 Ah[4][NKS];
#pragma unroll
    for (int a = 0; a < 4; ++a) {
        const float sA = (a == 2) ? (2.0f * LOG2E) : LOG2E;
        const int row = 64 * a + 16 * wv + cs;
#pragma unroll
        for (int ks = 0; ks < NKS; ++ks) {
            float v[8];
            if (ks < KSX) {
                if (FIRST) {
                    const float* p = Wih + (size_t)row * NFEAT;
#pragma unroll
                    for (int j = 0; j < 8; ++j) v[j] = (rq == 0) ? p[j] : 0.0f;
                } else {
                    const float* p = Wih + (size_t)row * HID + 32 * ks + 8 * rq;
#pragma unroll
                    for (int j = 0; j < 8; ++j) v[j] = p[j];
                }
            } else {
                const float* p = Whh + (size_t)row * HID + 32 * (ks - KSX) + 8 * rq;
#pragma unroll
                for (int j = 0; j < 8; ++j) v[j] = p[j];
            }
#pragma unroll
            for (int j = 0; j < 8; ++j) Ah[a][ks][j] = (_Float16)(v[j] * sA);
        }
    }

    // ---- bias (C/D layout), scaled — MFMA C-init ----
    f4 bias[4];
#pragma unroll
    for (int a = 0; a < 4; ++a) {
        const float sA = (a == 2) ? (2.0f * LOG2E) : LOG2E;
        f4 b = *(const f4*)(bi + 64 * a + hb) + *(const f4*)(bh_ + 64 * a + hb);
#pragma unroll
        for (int r = 0; r < 4; ++r) b[r] *= sA;
        bias[a] = b;
    }

    // ---- zero both zh planes (4096 B = 1024 u32) ----
#pragma unroll
    for (int i = 0; i < 4; ++i)
        ((u32*)zh)[tid * 4 + i] = 0u;

    float c0a = 0.f, c0b = 0.f;   // 2 cells per lane (fold)
    f4 acc[4];

    // ---- single prefetch set (consume -> refill; 1-step latency window) ----
    h8 xS[KSX];
    f4 fS[2];

    auto PREF = [&](int t) {
        if constexpr (FIRST) {
            if (rq == 0) {
                const float* pX = Xj + ((size_t)seq * TT + t) * NFEAT;
                fS[0] = *(const f4*)pX;
                fS[1] = *(const f4*)(pX + 4);
            } else {
                fS[0] = z4; fS[1] = z4;
            }
        } else {
            const unsigned short* pR = rbuf + ((size_t)seq * TT + t) * HID + 8 * rq;
#pragma unroll
            for (int ks = 0; ks < KSX; ++ks)
                xS[ks] = *(const h8*)(pR + 32 * ks);
        }
    };

    // x-part MFMAs: acc = bias + Wx*x (consumes xS/fS)
    auto XMF = [&]() {
        h8 bx[KSX];
        if constexpr (FIRST) {
#pragma unroll
            for (int j = 0; j < 4; ++j) {
                bx[0][j]     = (_Float16)fS[0][j];
                bx[0][4 + j] = (_Float16)fS[1][j];
            }
        } else {
#pragma unroll
            for (int ks = 0; ks < KSX; ++ks) bx[ks] = xS[ks];
        }
#pragma unroll
        for (int a = 0; a < 4; ++a) {
            acc[a] = MFMA16(Ah[a][0], bx[0], bias[a], 0, 0, 0);
            if constexpr (KSX == 2)
                acc[a] = MFMA16(Ah[a][1], bx[1], acc[a], 0, 0, 0);
        }
    };

    auto STEPB = [&](int t, int p) {
        // ---- h B-fragments from LDS (swizzled) ----
        h8 bhh[2];
#pragma unroll
        for (int kk = 0; kk < 2; ++kk) {
            const int ho = p * 2048 + ((cs * 128 + 64 * kk + 16 * rq) ^ swz);
            bhh[kk] = *(const h8*)(zh + ho);
        }

        // ---- serial MFMA work: h-part only ----
        __builtin_amdgcn_s_setprio(1);
#pragma unroll
        for (int a = 0; a < 4; ++a) {
            acc[a] = MFMA16(Ah[a][KSX + 0], bhh[0], acc[a], 0, 0, 0);
            acc[a] = MFMA16(Ah[a][KSX + 1], bhh[1], acc[a], 0, 0, 0);
        }
        __builtin_amdgcn_s_setprio(0);

        // ---- gate fold: lanes cs>=8 take rows {2,3} of partner seq ----
        float ga0[4], ga1[4];
#pragma unroll
        for (int a = 0; a < 4; ++a) {
            float x2 = __shfl_xor(acc[a][2], 8);
            float x3 = __shfl_xor(acc[a][3], 8);
            ga0[a] = h0 ? x2 : acc[a][0];
            ga1[a] = h0 ? x3 : acc[a][1];
        }

        // ---- activations (scaled domain): 2 cells per lane ----
        float hv0, hv1;
        {
            float ig = sigm_s(ga0[0]), fg = sigm_s(ga0[1]);
            float gg = tanh_s(ga0[2]), og = sigm_s(ga0[3]);
            float cc = fg * c0a + ig * gg;
            c0a = cc;
            hv0 = og * tanh_s(cc * (2.0f * LOG2E));
        }
        {
            float ig = sigm_s(ga1[0]), fg = sigm_s(ga1[1]);
            float gg = tanh_s(ga1[2]), og = sigm_s(ga1[3]);
            float cc = fg * c0b + ig * gg;
            c0b = cc;
            hv1 = og * tanh_s(cc * (2.0f * LOG2E));
        }

        // ---- pack 2 fp16 in one op; write zh ping (both dup rows) + ws ----
        u32 ph = __builtin_bit_cast(u32, __builtin_amdgcn_cvt_pkrtz(hv0, hv1));
        const int elem = hb + 2 * h0;
        {
            const int base = (1 ^ p) * 2048;
            const int wo0 = base + ((seqL * 128 + 2 * elem) ^ swz);
            const int wo1 = base + (((seqL + 8) * 128 + 2 * elem) ^ swz);
            *(u32*)(zh + wo0) = ph;
            *(u32*)(zh + wo1) = ph;
        }
        if constexpr (!LAST) {
            *(u32*)(wbuf + ((size_t)seq * TT + t) * HID + elem) = ph;
        } else {
            if (t == TT - 1) {
                float o0 = __shfl_xor(hv0, 8);
                float o1 = __shfl_xor(hv1, 8);
                if (!h0) {
                    f4 hvec = {hv0, hv1, o0, o1};
                    *(f4*)(hs + cs * 68 + hb) = hvec;
                }
            }
        }

        // ---- shadow: x-MFMAs of t+1 (consume xS), refill xS with x(t+2) ----
        if (t + 1 < TT) XMF();
        if (t + 2 < TT) PREF(t + 2);

        STEP_BAR();
    };

    PREF(0);
    __syncthreads();   // drains vmcnt (PREF + prev-layer ws stores) + zh zero visible

    XMF();             // x-part of step 0 (consumes x(0))
    PREF(1);

#pragma unroll 1
    for (int tb = 0; tb < TT; tb += 2) {
        STEPB(tb,     0);
        STEPB(tb + 1, 1);
    }
}

__global__ __launch_bounds__(NTHR, 2)
void lstm_mfma16(const float* __restrict__ Xj,
                 const float* __restrict__ Wih0, const float* __restrict__ Whh0,
                 const float* __restrict__ bih0, const float* __restrict__ bhh0,
                 const float* __restrict__ WihR, const float* __restrict__ WhhR,
                 const float* __restrict__ bihR, const float* __restrict__ bhhR,
                 const float* __restrict__ Wout, const float* __restrict__ bout,
                 float* __restrict__ out,
                 unsigned short* __restrict__ ws0, unsigned short* __restrict__ ws1)
{
    __shared__ char smraw[8448];
    char*  zh = smraw;                    // [2][16][64] fp16
    float* hs = (float*)(smraw + 4096);   // [16][68] f32 (rows 0..7 used)

    const int tid  = threadIdx.x;
    const int seq0 = blockIdx.x * SPB;

    run_layer<1, true,  false>(Wih0, Whh0, bih0, bhh0, Xj, ws0, ws0, zh, hs, tid, seq0);
    run_layer<2, false, false>(WihR + (size_t)0 * 256 * HID, WhhR + (size_t)0 * 256 * HID,
                               bihR + 0 * 256, bhhR + 0 * 256, nullptr, ws0, ws1, zh, hs, tid, seq0);
    run_layer<2, false, false>(WihR + (size_t)1 * 256 * HID, WhhR + (size_t)1 * 256 * HID,
                               bihR + 1 * 256, bhhR + 1 * 256, nullptr, ws1, ws0, zh, hs, tid, seq0);
    run_layer<2, false, false>(WihR + (size_t)2 * 256 * HID, WhhR + (size_t)2 * 256 * HID,
                               bihR + 2 * 256, bhhR + 2 * 256, nullptr, ws0, ws1, zh, hs, tid, seq0);
    run_layer<2, false, true >(WihR + (size_t)3 * 256 * HID, WhhR + (size_t)3 * 256 * HID,
                               bihR + 3 * 256, bhhR + 3 * 256, nullptr, ws1, ws0, zh, hs, tid, seq0);

    __syncthreads();
    // ---- output projection: 8 seqs x 12 outs = 96 items ----
    for (int it = tid; it < SPB * TOUTC; it += NTHR) {
        int s = it / TOUTC, o = it % TOUTC;
        float sum = bout[o];
#pragma unroll 8
        for (int j = 0; j < HID; ++j)
            sum = fmaf(Wout[o * HID + j], hs[s * 68 + j], sum);
        out[(size_t)(seq0 + s) * TOUTC + o] = sum;
    }
}

extern "C" void kernel_launch(void* const* d_in, const int* in_sizes, int n_in,
                              void* d_out, int out_size, void* d_ws, size_t ws_size,
                              hipStream_t stream)
{
    const float* Xj   = (const float*)d_in[1];
    const float* Wih0 = (const float*)d_in[3];
    const float* Whh0 = (const float*)d_in[4];
    const float* bih0 = (const float*)d_in[5];
    const float* bhh0 = (const float*)d_in[6];
    const float* WihR = (const float*)d_in[7];
    const float* WhhR = (const float*)d_in[8];
    const float* bihR = (const float*)d_in[9];
    const float* bhhR = (const float*)d_in[10];
    const float* Wout = (const float*)d_in[11];
    const float* bout = (const float*)d_in[12];
    float* out = (float*)d_out;

    unsigned short* ws = (unsigned short*)d_ws;
    const size_t half_elems = (size_t)8192 * TT * HID;   // 33.5M shorts = 67 MB
    const bool dbuf = ws_size >= 2 * half_elems * sizeof(unsigned short);
    unsigned short* ws0 = ws;
    unsigned short* ws1 = dbuf ? (ws + half_elems) : ws;   // in-place fallback (R6-proven)

    lstm_mfma16<<<NBLK, NTHR, 0, stream>>>(Xj, Wih0, Whh0, bih0, bhh0,
                                           WihR, WhhR, bihR, bhhR,
                                           Wout, bout, out, ws0, ws1);
}

// Round 18
// 266.480 us; speedup vs baseline: 2.4976x; 1.7146x over previous
//
#include <hip/hip_runtime.h>
#include <cstddef>

#define HID 64
#define TT 64
#define NFEAT 8
#define TOUTC 12
#define SPB 16
#define NBLK 512
#define NTHR 256

typedef float f4 __attribute__((ext_vector_type(4)));
typedef _Float16 h8 __attribute__((ext_vector_type(8)));
typedef unsigned int u32;
typedef unsigned long long u64;

#define MFMA16 __builtin_amdgcn_mfma_f32_16x16x32_f16
#define LOG2E 1.44269504088896340736f

struct CellOut { float h, c; };

// Fused-rcp scaled-domain LSTM cell activation.
// Inputs: xi,xf,xo = log2e*gate; xg2 = 2log2e*gate; cin = cell state.
//   ig*gg = (Eg-1) * rcp((1+Ei)(1+Eg));  h = og*tanh(c) = (Ec-1)*rcp((1+Eo)(1+Ec))
// xc2 clamped at 100 so (1+Eo)(1+Ec) < 2^128 (no inf -> no NaN); tanh(34.6)==1 exactly.
__device__ __forceinline__ CellOut cell_act(float xi, float xf, float xg2, float xo, float cin) {
    float Ei = __builtin_amdgcn_exp2f(-xi);
    float Ef = __builtin_amdgcn_exp2f(-xf);
    float Eg = __builtin_amdgcn_exp2f(xg2);
    float Eo = __builtin_amdgcn_exp2f(-xo);
    float fg = __builtin_amdgcn_rcpf(1.0f + Ef);
    float P1 = (Eg - 1.0f) * __builtin_amdgcn_rcpf((1.0f + Ei) * (1.0f + Eg));
    float cc = fmaf(fg, cin, P1);
    float xc2 = fminf(cc * (2.0f * LOG2E), 100.0f);
    float Ec = __builtin_amdgcn_exp2f(xc2);
    CellOut r;
    r.c = cc;
    r.h = (Ec - 1.0f) * __builtin_amdgcn_rcpf((1.0f + Eo) * (1.0f + Ec));
    return r;
}

// Barrier: drain LDS, raw barrier, allow everything EXCEPT DS to cross.
#define STEP_BAR() do {                                         \
    asm volatile("s_waitcnt lgkmcnt(0)" ::: "memory");          \
    __builtin_amdgcn_s_barrier();                               \
    __builtin_amdgcn_sched_barrier(0x7F);                       \
} while (0)

// LDS: zh [2][16][64] fp16 (4096 B, swizzle byte ^= (cs&7)<<4), hs f32[16][68].
// ws:  fp16 [seq][t][HID]; double-buffered across layers (in-place fallback).
// MFMA 16x16x32 f16, single chain (W fp16-RN scaled by log2e / 2log2e):
//   acc = bias (C-init) + Wx*x(t+1)  [shadow, end of step t]
//   acc += Wh*h(t)                   [post-barrier serial work]
// A frag: row=l&15, k=8*(l>>4)+j. B frag: col=l&15. C/D: col=l&15, row=4*(l>>4)+r.
// Static indexing only (rule #20); running pointers for ws/Xj; zh offsets hoisted.
template<int KSX, bool FIRST, bool LAST>
__device__ __forceinline__ void run_layer(
    const float* __restrict__ Wih, const float* __restrict__ Whh,
    const float* __restrict__ bi,  const float* __restrict__ bh_,
    const float* __restrict__ Xj,
    const unsigned short* __restrict__ rbuf, unsigned short* __restrict__ wbuf,
    char* zh, float* hs, int tid, int seq0)
{
    constexpr int NKS = KSX + 2;
    const int lane = tid & 63;
    const int wv   = tid >> 6;
    const int cs   = lane & 15;
    const int rq   = lane >> 4;
    const int hb   = 16 * wv + 4 * rq;
    const int swz  = (cs & 7) << 4;
    const int seq  = seq0 + cs;

    f4 z4 = {0.f, 0.f, 0.f, 0.f};

    // ---- weight A-fragments: single fp16 (RN), pre-scaled (2log2e for gate g) ----
    h8 Ah[4][NKS];
#pragma unroll
    for (int a = 0; a < 4; ++a) {
        const float sA = (a == 2) ? (2.0f * LOG2E) : LOG2E;
        const int row = 64 * a + 16 * wv + cs;
#pragma unroll
        for (int ks = 0; ks < NKS; ++ks) {
            float v[8];
            if (ks < KSX) {
                if (FIRST) {
                    const float* p = Wih + (size_t)row * NFEAT;
#pragma unroll
                    for (int j = 0; j < 8; ++j) v[j] = (rq == 0) ? p[j] : 0.0f;
                } else {
                    const float* p = Wih + (size_t)row * HID + 32 * ks + 8 * rq;
#pragma unroll
                    for (int j = 0; j < 8; ++j) v[j] = p[j];
                }
            } else {
                const float* p = Whh + (size_t)row * HID + 32 * (ks - KSX) + 8 * rq;
#pragma unroll
                for (int j = 0; j < 8; ++j) v[j] = p[j];
            }
#pragma unroll
            for (int j = 0; j < 8; ++j) Ah[a][ks][j] = (_Float16)(v[j] * sA);
        }
    }

    // ---- bias (C/D layout), scaled — MFMA C-init ----
    f4 bias[4];
#pragma unroll
    for (int a = 0; a < 4; ++a) {
        const float sA = (a == 2) ? (2.0f * LOG2E) : LOG2E;
        f4 b = *(const f4*)(bi + 64 * a + hb) + *(const f4*)(bh_ + 64 * a + hb);
#pragma unroll
        for (int r = 0; r < 4; ++r) b[r] *= sA;
        bias[a] = b;
    }

    // ---- zero both zh planes (4096 B = 1024 u32) ----
#pragma unroll
    for (int i = 0; i < 4; ++i)
        ((u32*)zh)[tid * 4 + i] = 0u;

    f4 c0 = z4;
    f4 acc[4];

    // ---- hoisted zh byte offsets (read per plane; write to other plane) ----
    const int r00 = 0    + ((cs * 128 +  0 + 16 * rq) ^ swz);
    const int r01 = 0    + ((cs * 128 + 64 + 16 * rq) ^ swz);
    const int r10 = 2048 + ((cs * 128 +  0 + 16 * rq) ^ swz);
    const int r11 = 2048 + ((cs * 128 + 64 + 16 * rq) ^ swz);
    const int w0  = 2048 + ((cs * 128 + 2 * hb) ^ swz);   // write when p==0
    const int w1  = 0    + ((cs * 128 + 2 * hb) ^ swz);   // write when p==1

    // ---- running pointers (advance by stride each step) ----
    const float*          pX = FIRST ? (Xj + (size_t)seq * TT * NFEAT) : nullptr;
    const unsigned short* pR = FIRST ? nullptr : (rbuf + (size_t)seq * TT * HID + 8 * rq);
    unsigned short*       wq = LAST  ? nullptr : (wbuf + (size_t)seq * TT * HID + hb);

    // ---- static parity prefetch sets (E: even t, O: odd t) ----
    h8 xE[KSX], xO[KSX];
    f4 fE[2], fO[2];

    auto PREF = [&](h8 (&hx)[KSX], f4 (&fx)[2]) {
        if constexpr (FIRST) {
            if (rq == 0) {
                fx[0] = *(const f4*)pX;
                fx[1] = *(const f4*)(pX + 4);
            } else {
                fx[0] = z4; fx[1] = z4;
            }
            pX += NFEAT;
        } else {
#pragma unroll
            for (int ks = 0; ks < KSX; ++ks)
                hx[ks] = *(const h8*)(pR + 32 * ks);
            pR += HID;
        }
    };

    // x-part MFMAs: acc = bias + Wx*x  (consumes a named parity set)
    auto XMF = [&](h8 (&hx)[KSX], f4 (&fx)[2]) {
        h8 bx[KSX];
        if constexpr (FIRST) {
#pragma unroll
            for (int j = 0; j < 4; ++j) {
                bx[0][j]     = (_Float16)fx[0][j];
                bx[0][4 + j] = (_Float16)fx[1][j];
            }
        } else {
#pragma unroll
            for (int ks = 0; ks < KSX; ++ks) bx[ks] = hx[ks];
        }
#pragma unroll
        for (int a = 0; a < 4; ++a) {
            acc[a] = MFMA16(Ah[a][0], bx[0], bias[a], 0, 0, 0);
            if constexpr (KSX == 2)
                acc[a] = MFMA16(Ah[a][1], bx[1], acc[a], 0, 0, 0);
        }
    };

    // One timestep; ro0/ro1/wo hoisted consts per parity; xSh/fSh consumed by
    // shadow XMF (x of t+1); xRe/fRe refilled with x(t+2).
    auto STEPB = [&](int t, int ro0, int ro1, int wo,
                     h8 (&xSh)[KSX], f4 (&fSh)[2],
                     h8 (&xRe)[KSX], f4 (&fRe)[2]) {
        // ---- h B-fragments from LDS (swizzled) ----
        h8 bhh0 = *(const h8*)(zh + ro0);
        h8 bhh1 = *(const h8*)(zh + ro1);

        // ---- serial MFMA work: h-part only ----
        __builtin_amdgcn_s_setprio(1);
#pragma unroll
        for (int a = 0; a < 4; ++a) {
            acc[a] = MFMA16(Ah[a][KSX + 0], bhh0, acc[a], 0, 0, 0);
            acc[a] = MFMA16(Ah[a][KSX + 1], bhh1, acc[a], 0, 0, 0);
        }
        __builtin_amdgcn_s_setprio(0);

        // ---- activations (fused-rcp, scaled domain) + cell update ----
        float hv[4];
#pragma unroll
        for (int r = 0; r < 4; ++r) {
            CellOut co = cell_act(acc[0][r], acc[1][r], acc[2][r], acc[3][r], c0[r]);
            c0[r] = co.c;
            hv[r] = co.h;
        }

        // ---- pack 4 fp16 via 2 cvt_pkrtz; zh ping write, then ws ----
        u32 lo = __builtin_bit_cast(u32, __builtin_amdgcn_cvt_pkrtz(hv[0], hv[1]));
        u32 hi = __builtin_bit_cast(u32, __builtin_amdgcn_cvt_pkrtz(hv[2], hv[3]));
        u64 ph = (u64)lo | ((u64)hi << 32);
        *(u64*)(zh + wo) = ph;
        if constexpr (!LAST) {
            *(u64*)wq = ph;
            wq += HID;
        } else {
            if (t == TT - 1) {
                f4 hvec = {hv[0], hv[1], hv[2], hv[3]};
                *(f4*)(hs + cs * 68 + hb) = hvec;
            }
        }

        // ---- shadow work: x-MFMAs of t+1, prefetch t+2 ----
        if (t + 1 < TT) XMF(xSh, fSh);
        if (t + 2 < TT) PREF(xRe, fRe);

        STEP_BAR();
    };

    PREF(xE, fE);
    PREF(xO, fO);
    __syncthreads();   // drains vmcnt (PREFs + prev-layer ws stores) + zh zero visible

    XMF(xE, fE);       // x-part of step 0

#pragma unroll 1
    for (int tb = 0; tb < TT; tb += 2) {
        STEPB(tb,     r00, r01, w0, xO, fO, xE, fE);
        STEPB(tb + 1, r10, r11, w1, xE, fE, xO, fO);
    }
}

__global__ __launch_bounds__(NTHR, 2)
void lstm_mfma16(const float* __restrict__ Xj,
                 const float* __restrict__ Wih0, const float* __restrict__ Whh0,
                 const float* __restrict__ bih0, const float* __restrict__ bhh0,
                 const float* __restrict__ WihR, const float* __restrict__ WhhR,
                 const float* __restrict__ bihR, const float* __restrict__ bhhR,
                 const float* __restrict__ Wout, const float* __restrict__ bout,
                 float* __restrict__ out,
                 unsigned short* __restrict__ ws0, unsigned short* __restrict__ ws1)
{
    __shared__ char smraw[8448];
    char*  zh = smraw;                    // [2][16][64] fp16
    float* hs = (float*)(smraw + 4096);   // [16][68] f32

    const int tid  = threadIdx.x;
    const int seq0 = blockIdx.x * SPB;

    run_layer<1, true,  false>(Wih0, Whh0, bih0, bhh0, Xj, ws0, ws0, zh, hs, tid, seq0);
    run_layer<2, false, false>(WihR + (size_t)0 * 256 * HID, WhhR + (size_t)0 * 256 * HID,
                               bihR + 0 * 256, bhhR + 0 * 256, nullptr, ws0, ws1, zh, hs, tid, seq0);
    run_layer<2, false, false>(WihR + (size_t)1 * 256 * HID, WhhR + (size_t)1 * 256 * HID,
                               bihR + 1 * 256, bhhR + 1 * 256, nullptr, ws1, ws0, zh, hs, tid, seq0);
    run_layer<2, false, false>(WihR + (size_t)2 * 256 * HID, WhhR + (size_t)2 * 256 * HID,
                               bihR + 2 * 256, bhhR + 2 * 256, nullptr, ws0, ws1, zh, hs, tid, seq0);
    run_layer<2, false, true >(WihR + (size_t)3 * 256 * HID, WhhR + (size_t)3 * 256 * HID,
                               bihR + 3 * 256, bhhR + 3 * 256, nullptr, ws1, ws0, zh, hs, tid, seq0);

    __syncthreads();
    // ---- output projection: 16 seqs x 12 outs ----
    for (int it = tid; it < SPB * TOUTC; it += NTHR) {
        int s = it / TOUTC, o = it % TOUTC;
        float sum = bout[o];
#pragma unroll 8
        for (int j = 0; j < HID; ++j)
            sum = fmaf(Wout[o * HID + j], hs[s * 68 + j], sum);
        out[(size_t)(seq0 + s) * TOUTC + o] = sum;
    }
}

extern "C" void kernel_launch(void* const* d_in, const int* in_sizes, int n_in,
                              void* d_out, int out_size, void* d_ws, size_t ws_size,
                              hipStream_t stream)
{
    const float* Xj   = (const float*)d_in[1];
    const float* Wih0 = (const float*)d_in[3];
    const float* Whh0 = (const float*)d_in[4];
    const float* bih0 = (const float*)d_in[5];
    const float* bhh0 = (const float*)d_in[6];
    const float* WihR = (const float*)d_in[7];
    const float* WhhR = (const float*)d_in[8];
    const float* bihR = (const float*)d_in[9];
    const float* bhhR = (const float*)d_in[10];
    const float* Wout = (const float*)d_in[11];
    const float* bout = (const float*)d_in[12];
    float* out = (float*)d_out;

    unsigned short* ws = (unsigned short*)d_ws;
    const size_t half_elems = (size_t)8192 * TT * HID;   // 33.5M shorts = 67 MB
    const bool dbuf = ws_size >= 2 * half_elems * sizeof(unsigned short);
    unsigned short* ws0 = ws;
    unsigned short* ws1 = dbuf ? (ws + half_elems) : ws;   // in-place fallback (R6-proven)

    lstm_mfma16<<<NBLK, NTHR, 0, stream>>>(Xj, Wih0, Whh0, bih0, bhh0,
                                           WihR, WhhR, bihR, bhhR,
                                           Wout, bout, out, ws0, ws1);
}